// Round 1
// 5148.291 us; speedup vs baseline: 1.2804x; 1.2804x over previous
//
#include <hip/hip_runtime.h>
#include <math.h>

static inline int ceil_div(int a, int b) { return (a + b - 1) / b; }

typedef _Float16 f16x8 __attribute__((ext_vector_type(8)));
typedef _Float16 f16x4 __attribute__((ext_vector_type(4)));
typedef float f32x4 __attribute__((ext_vector_type(4)));

// ---------------- CSR build ----------------
__global__ __launch_bounds__(256) void k_hist(const int* __restrict__ rows, int* __restrict__ cnt, int E) {
  int e = blockIdx.x * 256 + threadIdx.x;
  if (e < E) atomicAdd(&cnt[rows[e]], 1);
}

__global__ __launch_bounds__(1024) void k_scan(const int* __restrict__ cnt, int* __restrict__ row_ptr,
                                               int* __restrict__ cursor, int n) {
  __shared__ int sums[1024];
  int t = threadIdx.x;
  int CH = (n + 1023) >> 10;
  int base = t * CH;
  int s = 0;
  for (int i = 0; i < CH; i++) { int idx = base + i; if (idx < n) s += cnt[idx]; }
  sums[t] = s;
  __syncthreads();
  for (int off = 1; off < 1024; off <<= 1) {
    int v = (t >= off) ? sums[t - off] : 0;
    __syncthreads();
    sums[t] += v;
    __syncthreads();
  }
  int run = (t == 0) ? 0 : sums[t - 1];
  for (int i = 0; i < CH; i++) {
    int idx = base + i;
    if (idx < n) { row_ptr[idx] = run; cursor[idx] = run; run += cnt[idx]; }
  }
  if (t == 1023) row_ptr[n] = run;
}

__global__ __launch_bounds__(256) void k_scatter(const int* __restrict__ rows, const int* __restrict__ cols,
    const float* __restrict__ vals, int* __restrict__ cursor,
    int* __restrict__ csr_col, float* __restrict__ csr_val, int E) {
  int e = blockIdx.x * 256 + threadIdx.x;
  if (e < E) {
    int r = rows[e];
    int p = atomicAdd(&cursor[r], 1);
    csr_col[p] = cols[e];
    csr_val[p] = vals[e];
  }
}

// ---------------- fp32 -> (f16 hi, f16 lo) split, elementwise, float4-vectorized ----------------
__global__ __launch_bounds__(256) void k_split4(const float* __restrict__ in,
    _Float16* __restrict__ o0, _Float16* __restrict__ o1, long n4) {
  long i = (long)blockIdx.x * 256 + threadIdx.x;
  if (i >= n4) return;
  float4 v = *(const float4*)(in + i * 4);
  f16x4 h, l;
  h[0] = (_Float16)v.x; l[0] = (_Float16)(v.x - (float)h[0]);
  h[1] = (_Float16)v.y; l[1] = (_Float16)(v.y - (float)h[1]);
  h[2] = (_Float16)v.z; l[2] = (_Float16)(v.z - (float)h[2]);
  h[3] = (_Float16)v.w; l[3] = (_Float16)(v.w - (float)h[3]);
  *(f16x4*)(o0 + i * 4) = h;
  *(f16x4*)(o1 + i * 4) = l;
}

// ---------------- W [K,M] fp32 -> transposed split Wt [M_pad][lda] f16 hi/lo (zero-padded) ----------------
__global__ __launch_bounds__(256) void k_splitT(const float* __restrict__ W,
    _Float16* __restrict__ o0, _Float16* __restrict__ o1, int K, int M, int lda) {
  int k = blockIdx.x * 256 + threadIdx.x;
  int m = blockIdx.y;
  if (k >= lda) return;
  float v = (k < K && m < M) ? W[(long)k * M + m] : 0.f;
  _Float16 h = (_Float16)v;
  _Float16 l = (_Float16)(v - (float)h);
  o0[(long)m * lda + k] = h;
  o1[(long)m * lda + k] = l;
}

// ---------------- split-f16 MFMA GEMM: C[N,M] = (A0+A1)[N,K] @ (B0+B1)^T, 3-term ----------------
// A: row-major [N][lda] f16 pairs. B: transposed row-major [M_pad][ldb] f16 pairs.
// 128x128 tile, BK=32, 4 waves, 16x16x32 f16 MFMA, XOR-swizzled LDS (2-way = free).
// Fragment layouts (guide §3, m89-verified family):
//   A: row = lane&15, k = (lane>>4)*8 + e ;  B: col = lane&15, k = (lane>>4)*8 + e
//   D: col = lane&15, row = (lane>>4)*4 + reg
__global__ __launch_bounds__(256) void k_gemm_sp(
    const _Float16* __restrict__ A0, const _Float16* __restrict__ A1, int lda,
    const _Float16* __restrict__ B0, const _Float16* __restrict__ B1, int ldb,
    float* __restrict__ C, int N, int K, int M, int relu) {
  __shared__ __align__(16) short As0[4096];
  __shared__ __align__(16) short As1[4096];
  __shared__ __align__(16) short Bs0[4096];
  __shared__ __align__(16) short Bs1[4096];
  const int tid = threadIdx.x;
  const int lane = tid & 63;
  const int w = tid >> 6;
  const int wr = (w >> 1) << 6;   // 0 or 64 (row half)
  const int wc = (w & 1) << 6;    // 0 or 64 (col half)
  const long rowBase = (long)blockIdx.y * 128;
  const long colBase = (long)blockIdx.x * 128;

  f32x4 acc[4][4];
#pragma unroll
  for (int i = 0; i < 4; i++)
#pragma unroll
    for (int j = 0; j < 4; j++) acc[i][j] = (f32x4){0.f, 0.f, 0.f, 0.f};

  // fragment read offsets (swizzled): slot' = slot ^ ((row>>1)&3)
  int aoff[4], boff[4];
#pragma unroll
  for (int i = 0; i < 4; i++) {
    int r = wr + i * 16 + (lane & 15);
    aoff[i] = r * 32 + (((lane >> 4) ^ ((r >> 1) & 3)) << 3);
    int c = wc + i * 16 + (lane & 15);
    boff[i] = c * 32 + (((lane >> 4) ^ ((c >> 1) & 3)) << 3);
  }
  const int srow0 = tid >> 2;   // 0..63
  const int sch = tid & 3;      // 16B chunk within 32-k row

  for (int k0 = 0; k0 < K; k0 += 32) {
    const bool full = (k0 + 32 <= K);
#pragma unroll
    for (int it = 0; it < 2; ++it) {
      int row = it * 64 + srow0;
      int sIdx = row * 32 + ((sch ^ ((row >> 1) & 3)) << 3);
      long ga = rowBase + row; if (ga >= N) ga = N - 1;   // clamp; guarded rows never stored
      long gb = colBase + row;                            // B rows zero-padded to M_pad
      long offA = ga * (long)lda + k0 + sch * 8;
      long offB = gb * (long)ldb + k0 + sch * 8;
      if (full) {
        // A via 2x int2 (lda may be 500 -> rows only 8B-aligned); B via int4 (ldb 16B-aligned)
        int2 a0a = *(const int2*)(A0 + offA);
        int2 a0b = *(const int2*)(A0 + offA + 4);
        int2 a1a = *(const int2*)(A1 + offA);
        int2 a1b = *(const int2*)(A1 + offA + 4);
        int4 b0v = *(const int4*)(B0 + offB);
        int4 b1v = *(const int4*)(B1 + offB);
        *(int2*)&As0[sIdx] = a0a; *(int2*)&As0[sIdx + 4] = a0b;
        *(int2*)&As1[sIdx] = a1a; *(int2*)&As1[sIdx + 4] = a1b;
        *(int4*)&Bs0[sIdx] = b0v;
        *(int4*)&Bs1[sIdx] = b1v;
      } else {
        f16x8 va0, va1, vb0, vb1;
        int kb = k0 + sch * 8;
#pragma unroll
        for (int q = 0; q < 8; q++) {
          bool ok = (kb + q) < K;
          va0[q] = ok ? A0[offA + q] : (_Float16)0.f;
          va1[q] = ok ? A1[offA + q] : (_Float16)0.f;
          vb0[q] = ok ? B0[offB + q] : (_Float16)0.f;
          vb1[q] = ok ? B1[offB + q] : (_Float16)0.f;
        }
        *(f16x8*)&As0[sIdx] = va0;
        *(f16x8*)&As1[sIdx] = va1;
        *(f16x8*)&Bs0[sIdx] = vb0;
        *(f16x8*)&Bs1[sIdx] = vb1;
      }
    }
    __syncthreads();
    f16x8 a0[4], a1[4], b0[4], b1[4];
#pragma unroll
    for (int i = 0; i < 4; i++) {
      a0[i] = *(const f16x8*)&As0[aoff[i]];
      a1[i] = *(const f16x8*)&As1[aoff[i]];
      b0[i] = *(const f16x8*)&Bs0[boff[i]];
      b1[i] = *(const f16x8*)&Bs1[boff[i]];
    }
#pragma unroll
    for (int i = 0; i < 4; i++)
#pragma unroll
      for (int j = 0; j < 4; j++) {
        acc[i][j] = __builtin_amdgcn_mfma_f32_16x16x32_f16(a0[i], b0[j], acc[i][j], 0, 0, 0);
        acc[i][j] = __builtin_amdgcn_mfma_f32_16x16x32_f16(a0[i], b1[j], acc[i][j], 0, 0, 0);
        acc[i][j] = __builtin_amdgcn_mfma_f32_16x16x32_f16(a1[i], b0[j], acc[i][j], 0, 0, 0);
      }
    __syncthreads();
  }

#pragma unroll
  for (int i = 0; i < 4; i++) {
    long gr0 = rowBase + wr + i * 16 + ((lane >> 4) << 2);
#pragma unroll
    for (int j = 0; j < 4; j++) {
      long gc = colBase + wc + j * 16 + (lane & 15);
      if (gc < M) {
#pragma unroll
        for (int r = 0; r < 4; r++) {
          long gr = gr0 + r;
          if (gr < N) {
            float v = acc[i][j][r];
            if (relu) v = fmaxf(v, 0.f);
            C[gr * (long)M + gc] = v;
          }
        }
      }
    }
  }
}

// ---------------- SpMM, width d <= 512 (d % 4 == 0), one block per row; optional split-f16 output ----------------
__global__ __launch_bounds__(128) void k_spmm_vec(const int* __restrict__ rp, const int* __restrict__ ci,
    const float* __restrict__ cv, const float* __restrict__ src, float* __restrict__ dst,
    _Float16* __restrict__ o0, _Float16* __restrict__ o1, int ldo,
    int d, int relu, int splitOut) {
  int r = blockIdx.x;
  int c4 = threadIdx.x * 4;
  if (c4 >= d) return;
  int s = rp[r], e = rp[r + 1];
  float4 acc = make_float4(0.f, 0.f, 0.f, 0.f);
  for (int j = s; j < e; j++) {
    int c = ci[j];
    float v = cv[j];
    float4 xv = *(const float4*)(src + (long)c * d + c4);
    acc.x += v * xv.x; acc.y += v * xv.y; acc.z += v * xv.z; acc.w += v * xv.w;
  }
  if (relu) {
    acc.x = fmaxf(acc.x, 0.f); acc.y = fmaxf(acc.y, 0.f);
    acc.z = fmaxf(acc.z, 0.f); acc.w = fmaxf(acc.w, 0.f);
  }
  if (splitOut) {
    f16x4 h, l;
    h[0] = (_Float16)acc.x; l[0] = (_Float16)(acc.x - (float)h[0]);
    h[1] = (_Float16)acc.y; l[1] = (_Float16)(acc.y - (float)h[1]);
    h[2] = (_Float16)acc.z; l[2] = (_Float16)(acc.z - (float)h[2]);
    h[3] = (_Float16)acc.w; l[3] = (_Float16)(acc.w - (float)h[3]);
    *(f16x4*)&o0[(long)r * ldo + c4] = h;
    *(f16x4*)&o1[(long)r * ldo + c4] = l;
  } else {
    *(float4*)(dst + (long)r * d + c4) = acc;
  }
}

// ---------------- SpMM width 10, one thread per row; optional relu / final softmax ----------------
__global__ __launch_bounds__(256) void k_spmm10(const int* __restrict__ rp, const int* __restrict__ ci,
    const float* __restrict__ cv, const float* __restrict__ src, float* __restrict__ dst,
    int n, int relu, int soft) {
  int r = blockIdx.x * 256 + threadIdx.x;
  if (r >= n) return;
  int s = rp[r], e = rp[r + 1];
  float acc[10] = {0.f, 0.f, 0.f, 0.f, 0.f, 0.f, 0.f, 0.f, 0.f, 0.f};
  for (int j = s; j < e; j++) {
    int c = ci[j];
    float v = cv[j];
    const float* p = src + (long)c * 10;
#pragma unroll
    for (int m = 0; m < 10; m++) acc[m] += v * p[m];
  }
  if (relu) {
#pragma unroll
    for (int m = 0; m < 10; m++) acc[m] = fmaxf(acc[m], 0.f);
  }
  if (soft) {
    float mx = acc[0];
#pragma unroll
    for (int m = 1; m < 10; m++) mx = fmaxf(mx, acc[m]);
    float ssum = 0.f;
#pragma unroll
    for (int m = 0; m < 10; m++) { acc[m] = expf(acc[m] - mx); ssum += acc[m]; }
    float inv = 1.f / ssum;
#pragma unroll
    for (int m = 0; m < 10; m++) acc[m] *= inv;
  }
  float* q = dst + (long)r * 10;
#pragma unroll
  for (int m = 0; m < 10; m++) q[m] = acc[m];
}

// ---------------- gate (2-way) + combine: c = m0*z + m1*h ; fp32 out OR split-f16 out ----------------
__global__ __launch_bounds__(128) void k_gate_combine(const float* __restrict__ h, const float* __restrict__ zin,
    const float* __restrict__ Wm, const float* __restrict__ bm,
    float* __restrict__ cout, _Float16* __restrict__ o0, _Float16* __restrict__ o1, int ldo,
    int d, int splitOut) {
  __shared__ float red[2][2];
  __shared__ float mbc[2];
  int r = blockIdx.x, tid = threadIdx.x;
  const float* hrow = h + (long)r * d;
  const float* zrow = zin + (long)r * d;
  float s0 = 0.f, s1 = 0.f;
  for (int i = tid * 4; i < d; i += 512) {
    float4 hv = *(const float4*)(hrow + i);
    float4 zv = *(const float4*)(zrow + i);
    float4 wa = *(const float4*)(Wm + i * 2);
    float4 wb = *(const float4*)(Wm + i * 2 + 4);
    s0 += hv.x * wa.x + hv.y * wa.z + hv.z * wb.x + hv.w * wb.z;
    s1 += hv.x * wa.y + hv.y * wa.w + hv.z * wb.y + hv.w * wb.w;
    float4 wc = *(const float4*)(Wm + (d + i) * 2);
    float4 wd = *(const float4*)(Wm + (d + i) * 2 + 4);
    s0 += zv.x * wc.x + zv.y * wc.z + zv.z * wd.x + zv.w * wd.z;
    s1 += zv.x * wc.y + zv.y * wc.w + zv.z * wd.y + zv.w * wd.w;
  }
  for (int off = 32; off > 0; off >>= 1) { s0 += __shfl_down(s0, off); s1 += __shfl_down(s1, off); }
  int wave = tid >> 6, lane = tid & 63;
  if (lane == 0) { red[wave][0] = s0; red[wave][1] = s1; }
  __syncthreads();
  if (tid == 0) {
    float l0 = red[0][0] + red[1][0] + bm[0];
    float l1 = red[0][1] + red[1][1] + bm[1];
    l0 = (l0 > 0.f) ? l0 : 0.01f * l0;
    l1 = (l1 > 0.f) ? l1 : 0.01f * l1;
    float mx = fmaxf(l0, l1);
    float e0 = expf(l0 - mx), e1 = expf(l1 - mx);
    float inv = 1.f / (e0 + e1);
    float m0 = e0 * inv, m1 = e1 * inv;
    float nrm = fmaxf(sqrtf(m0 * m0 + m1 * m1), 1e-12f);
    mbc[0] = m0 / nrm; mbc[1] = m1 / nrm;
  }
  __syncthreads();
  float m0 = mbc[0], m1 = mbc[1];
  for (int i = tid * 4; i < d; i += 512) {
    float4 hv = *(const float4*)(hrow + i);
    float4 zv = *(const float4*)(zrow + i);
    float4 o;
    o.x = m0 * zv.x + m1 * hv.x;
    o.y = m0 * zv.y + m1 * hv.y;
    o.z = m0 * zv.z + m1 * hv.z;
    o.w = m0 * zv.w + m1 * hv.w;
    if (splitOut) {
      f16x4 hh, ll;
      hh[0] = (_Float16)o.x; ll[0] = (_Float16)(o.x - (float)hh[0]);
      hh[1] = (_Float16)o.y; ll[1] = (_Float16)(o.y - (float)hh[1]);
      hh[2] = (_Float16)o.z; ll[2] = (_Float16)(o.z - (float)hh[2]);
      hh[3] = (_Float16)o.w; ll[3] = (_Float16)(o.w - (float)hh[3]);
      *(f16x4*)&o0[(long)r * ldo + i] = hh;
      *(f16x4*)&o1[(long)r * ldo + i] = ll;
    } else {
      *(float4*)(cout + (long)r * d + i) = o;
    }
  }
}

// ---------------- layer-3 gate + fused (m0*z3 + m1*h3) @ W4 (2000x10), one block per row ----------------
__global__ __launch_bounds__(256) void k_gate4(const float* __restrict__ h3, const float* __restrict__ z3,
    const float* __restrict__ Wm3, const float* __restrict__ bm3,
    const float* __restrict__ W4, float* __restrict__ outv) {
  __shared__ float w4s[10000];   // 1000 rows x 10 per chunk
  __shared__ float red[4][10];
  __shared__ float mbc[2];
  int r = blockIdx.x, tid = threadIdx.x;
  const float* hrow = h3 + (long)r * 2000;
  const float* zrow = z3 + (long)r * 2000;
  float s0 = 0.f, s1 = 0.f;
  for (int i = tid * 4; i < 2000; i += 1024) {
    float4 hv = *(const float4*)(hrow + i);
    float4 zv = *(const float4*)(zrow + i);
    float4 wa = *(const float4*)(Wm3 + i * 2);
    float4 wb = *(const float4*)(Wm3 + i * 2 + 4);
    s0 += hv.x * wa.x + hv.y * wa.z + hv.z * wb.x + hv.w * wb.z;
    s1 += hv.x * wa.y + hv.y * wa.w + hv.z * wb.y + hv.w * wb.w;
    float4 wc = *(const float4*)(Wm3 + (2000 + i) * 2);
    float4 wd = *(const float4*)(Wm3 + (2000 + i) * 2 + 4);
    s0 += zv.x * wc.x + zv.y * wc.z + zv.z * wd.x + zv.w * wd.z;
    s1 += zv.x * wc.y + zv.y * wc.w + zv.z * wd.y + zv.w * wd.w;
  }
  for (int off = 32; off > 0; off >>= 1) { s0 += __shfl_down(s0, off); s1 += __shfl_down(s1, off); }
  int wave = tid >> 6, lane = tid & 63;
  if (lane == 0) { red[wave][0] = s0; red[wave][1] = s1; }
  __syncthreads();
  if (tid == 0) {
    float l0 = red[0][0] + red[1][0] + red[2][0] + red[3][0] + bm3[0];
    float l1 = red[0][1] + red[1][1] + red[2][1] + red[3][1] + bm3[1];
    l0 = (l0 > 0.f) ? l0 : 0.01f * l0;
    l1 = (l1 > 0.f) ? l1 : 0.01f * l1;
    float mx = fmaxf(l0, l1);
    float e0 = expf(l0 - mx), e1 = expf(l1 - mx);
    float inv = 1.f / (e0 + e1);
    float m0 = e0 * inv, m1 = e1 * inv;
    float nrm = fmaxf(sqrtf(m0 * m0 + m1 * m1), 1e-12f);
    mbc[0] = m0 / nrm; mbc[1] = m1 / nrm;
  }
  __syncthreads();
  float m0 = mbc[0], m1 = mbc[1];
  float acc[10] = {0.f, 0.f, 0.f, 0.f, 0.f, 0.f, 0.f, 0.f, 0.f, 0.f};
  for (int ch = 0; ch < 2; ch++) {
    __syncthreads();
    for (int i = tid; i < 10000; i += 256) w4s[i] = W4[ch * 10000 + i];
    __syncthreads();
    int base = ch * 1000;
    for (int i = tid * 4; i < 1000; i += 1024) {
      float4 hv = *(const float4*)(hrow + base + i);
      float4 zv = *(const float4*)(zrow + base + i);
      float c0 = m0 * zv.x + m1 * hv.x;
      float c1 = m0 * zv.y + m1 * hv.y;
      float c2 = m0 * zv.z + m1 * hv.z;
      float c3 = m0 * zv.w + m1 * hv.w;
      const float* w0 = &w4s[i * 10];
#pragma unroll
      for (int m = 0; m < 10; m++)
        acc[m] += c0 * w0[m] + c1 * w0[10 + m] + c2 * w0[20 + m] + c3 * w0[30 + m];
    }
  }
  for (int off = 32; off > 0; off >>= 1) {
#pragma unroll
    for (int m = 0; m < 10; m++) acc[m] += __shfl_down(acc[m], off);
  }
  if (lane == 0) {
#pragma unroll
    for (int m = 0; m < 10; m++) red[wave][m] = acc[m];
  }
  __syncthreads();
  if (tid < 10) outv[(long)r * 10 + tid] = red[0][tid] + red[1][tid] + red[2][tid] + red[3][tid];
}

// ---------------- final 5-way gate (u) + fused @ W5 (3020x10), one block per row ----------------
__global__ __launch_bounds__(256) void k_uy(const float* __restrict__ z1, const float* __restrict__ z2,
    const float* __restrict__ z3, const float* __restrict__ z4, const float* __restrict__ zin,
    const float* __restrict__ Wml, const float* __restrict__ bml,
    const float* __restrict__ W5, float* __restrict__ y) {
  __shared__ float cat[3020];
  __shared__ float red[4][10];
  __shared__ float ubc[5];
  int r = blockIdx.x, tid = threadIdx.x;
  for (int i = tid; i < 500; i += 256) {
    cat[i] = z1[(long)r * 500 + i];
    cat[500 + i] = z2[(long)r * 500 + i];
  }
  for (int i = tid; i < 2000; i += 256) cat[1000 + i] = z3[(long)r * 2000 + i];
  if (tid < 10) cat[3000 + tid] = z4[(long)r * 10 + tid];
  if (tid >= 16 && tid < 26) cat[3010 + tid - 16] = zin[(long)r * 10 + tid - 16];
  __syncthreads();
  float l[5] = {0.f, 0.f, 0.f, 0.f, 0.f};
  for (int i = tid; i < 3020; i += 256) {
    float c = cat[i];
    const float* w = Wml + (long)i * 5;
    l[0] += c * w[0]; l[1] += c * w[1]; l[2] += c * w[2]; l[3] += c * w[3]; l[4] += c * w[4];
  }
  for (int off = 32; off > 0; off >>= 1) {
#pragma unroll
    for (int m = 0; m < 5; m++) l[m] += __shfl_down(l[m], off);
  }
  int wave = tid >> 6, lane = tid & 63;
  if (lane == 0) {
#pragma unroll
    for (int m = 0; m < 5; m++) red[wave][m] = l[m];
  }
  __syncthreads();
  if (tid == 0) {
    float u[5];
    float mx = -1e30f;
#pragma unroll
    for (int m = 0; m < 5; m++) {
      float t = red[0][m] + red[1][m] + red[2][m] + red[3][m] + bml[m];
      t = (t > 0.f) ? t : 0.01f * t;
      u[m] = t;
      mx = fmaxf(mx, t);
    }
    float s = 0.f;
#pragma unroll
    for (int m = 0; m < 5; m++) { u[m] = expf(u[m] - mx); s += u[m]; }
    float inv = 1.f / s;
    float n2 = 0.f;
#pragma unroll
    for (int m = 0; m < 5; m++) { u[m] *= inv; n2 += u[m] * u[m]; }
    float nrm = fmaxf(sqrtf(n2), 1e-12f);
#pragma unroll
    for (int m = 0; m < 5; m++) ubc[m] = u[m] / nrm;
  }
  __syncthreads();
  for (int i = tid; i < 3020; i += 256) {
    int seg = (i < 500) ? 0 : (i < 1000) ? 1 : (i < 3000) ? 2 : (i < 3010) ? 3 : 4;
    cat[i] *= ubc[seg];
  }
  __syncthreads();
  float acc[10] = {0.f, 0.f, 0.f, 0.f, 0.f, 0.f, 0.f, 0.f, 0.f, 0.f};
  for (int i = tid; i < 3020; i += 256) {
    float c = cat[i];
    const float* w = W5 + (long)i * 10;
#pragma unroll
    for (int m = 0; m < 10; m++) acc[m] += c * w[m];
  }
  for (int off = 32; off > 0; off >>= 1) {
#pragma unroll
    for (int m = 0; m < 10; m++) acc[m] += __shfl_down(acc[m], off);
  }
  if (lane == 0) {
#pragma unroll
    for (int m = 0; m < 10; m++) red[wave][m] = acc[m];
  }
  __syncthreads();
  if (tid < 10) y[(long)r * 10 + tid] = red[0][tid] + red[1][tid] + red[2][tid] + red[3][tid];
}

extern "C" void kernel_launch(void* const* d_in, const int* in_sizes, int n_in,
                              void* d_out, int out_size, void* d_ws, size_t ws_size,
                              hipStream_t stream) {
  const float* x   = (const float*)d_in[0];
  const int* arow  = (const int*)d_in[1];
  const int* acol  = (const int*)d_in[2];
  const float* aval = (const float*)d_in[3];
  const float* h1  = (const float*)d_in[4];
  const float* h2  = (const float*)d_in[5];
  const float* h3  = (const float*)d_in[6];
  const float* zf  = (const float*)d_in[7];
  const float* W1  = (const float*)d_in[8];
  const float* W2  = (const float*)d_in[9];
  const float* W3  = (const float*)d_in[10];
  const float* W4  = (const float*)d_in[11];
  const float* W5  = (const float*)d_in[12];
  const float* Wm1 = (const float*)d_in[13];
  const float* bm1 = (const float*)d_in[14];
  const float* Wm2 = (const float*)d_in[15];
  const float* bm2 = (const float*)d_in[16];
  const float* Wm3 = (const float*)d_in[17];
  const float* bm3 = (const float*)d_in[18];
  const float* Wml = (const float*)d_in[19];
  const float* bml = (const float*)d_in[20];
  const int E = in_sizes[1];
  const int N = in_sizes[4] / 500;
  float* out = (float*)d_out;

  // workspace carve — identical footprint to the previous (passing) version (~819.4 MB)
  char* p = (char*)d_ws;
  auto alloc = [&](size_t bytes) { char* q = p; p += (bytes + 255) & ~(size_t)255; return q; };
  float* z1      = (float*)alloc((size_t)N * 500 * 4);
  float* z2      = (float*)alloc((size_t)N * 500 * 4);   // head also aliases Wt1/Wt2 (dead before spmm2 writes z2)
  float* z3      = (float*)alloc((size_t)N * 2000 * 4);  // aliases x0/x1 f16 splits (dead after gemm1)
  float* tA      = (float*)alloc((size_t)N * 500 * 4);
  _Float16* cs0  = (_Float16*)alloc((size_t)N * 500 * 2);  // A hi for gemm2 (c1) then gemm3 (s3)
  _Float16* cs1  = (_Float16*)alloc((size_t)N * 500 * 2);  // A lo
  float* xw4     = (float*)alloc((size_t)N * 10 * 4);    // xw4..yb span also aliases Wt3 (dead before gate4)
  float* z4      = (float*)alloc((size_t)N * 10 * 4);
  float* yb      = (float*)alloc((size_t)N * 10 * 4);
  int* cnt       = (int*)alloc((size_t)N * 4);
  int* row_ptr   = (int*)alloc((size_t)(N + 1) * 4);
  int* cursor    = (int*)alloc((size_t)N * 4);
  int* csr_col   = (int*)alloc((size_t)E * 4);
  float* csr_val = (float*)alloc((size_t)E * 4);

  // aliases (lifetime-disjoint, see timeline in comments above)
  _Float16* x0 = (_Float16*)z3;                         // [N][2000] f16 hi
  _Float16* x1 = x0 + (size_t)N * 2000;                 // [N][2000] f16 lo
  _Float16* Wt1_0 = (_Float16*)z2;                      // [512][2000]
  _Float16* Wt1_1 = Wt1_0 + (size_t)512 * 2000;
  _Float16* Wt2_0 = Wt1_1 + (size_t)512 * 2000;         // [512][504]
  _Float16* Wt2_1 = Wt2_0 + (size_t)512 * 504;
  _Float16* Wt3_0 = (_Float16*)xw4;                     // [2048][504]
  _Float16* Wt3_1 = Wt3_0 + (size_t)2048 * 504;

  // CSR build
  hipMemsetAsync(cnt, 0, (size_t)N * 4, stream);
  k_hist<<<ceil_div(E, 256), 256, 0, stream>>>(arow, cnt, E);
  k_scan<<<1, 1024, 0, stream>>>(cnt, row_ptr, cursor, N);
  k_scatter<<<ceil_div(E, 256), 256, 0, stream>>>(arow, acol, aval, cursor, csr_col, csr_val, E);

  // weight transpose + f16 split (tiny)
  k_splitT<<<dim3(ceil_div(2000, 256), 512), 256, 0, stream>>>(W1, Wt1_0, Wt1_1, 2000, 500, 2000);
  k_splitT<<<dim3(ceil_div(504, 256), 512), 256, 0, stream>>>(W2, Wt2_0, Wt2_1, 500, 500, 504);
  k_splitT<<<dim3(ceil_div(504, 256), 2048), 256, 0, stream>>>(W3, Wt3_0, Wt3_1, 500, 2000, 504);
  // x split (400 MB -> 2x200 MB f16)
  {
    long n4 = (long)N * 2000 / 4;
    k_split4<<<(int)((n4 + 255) / 256), 256, 0, stream>>>(x, x0, x1, n4);
  }

  // grid: blockIdx.x = col tile (fast-varying) so col-tiles sharing an A row-panel run together (L2/L3 reuse)
  dim3 gA(ceil_div(500, 128), ceil_div(N, 128));
  dim3 gC(ceil_div(2000, 128), ceil_div(N, 128));

  // layer 1: tA = x@W1 ; z1 = relu(spmm(tA))
  k_gemm_sp<<<gA, 256, 0, stream>>>(x0, x1, 2000, Wt1_0, Wt1_1, 2000, tA, N, 2000, 500, 0);
  k_spmm_vec<<<N, 128, 0, stream>>>(row_ptr, csr_col, csr_val, tA, z1, nullptr, nullptr, 0, 500, 1, 0);
  // gate1 + combine -> split f16 (cs0/cs1)
  k_gate_combine<<<N, 128, 0, stream>>>(h1, z1, Wm1, bm1, nullptr, cs0, cs1, 500, 500, 1);
  // layer 2: tA = c1@W2 ; z2 = relu(spmm(tA))   (spmm2 overwrites Wt1/Wt2 region — both dead)
  k_gemm_sp<<<gA, 256, 0, stream>>>(cs0, cs1, 500, Wt2_0, Wt2_1, 504, tA, N, 500, 500, 0);
  k_spmm_vec<<<N, 128, 0, stream>>>(row_ptr, csr_col, csr_val, tA, z2, nullptr, nullptr, 0, 500, 1, 0);
  // gate2 + combine -> fp32 tA
  k_gate_combine<<<N, 128, 0, stream>>>(h2, z2, Wm2, bm2, tA, nullptr, nullptr, 0, 500, 0);
  // layer 3 (reordered): s3 = spmm(c2) -> split f16 ; z3 = relu(s3@W3)  (z3 overwrites x0/x1 — dead)
  k_spmm_vec<<<N, 128, 0, stream>>>(row_ptr, csr_col, csr_val, tA, nullptr, cs0, cs1, 500, 500, 0, 1);
  k_gemm_sp<<<gC, 256, 0, stream>>>(cs0, cs1, 500, Wt3_0, Wt3_1, 504, z3, N, 500, 2000, 1);
  // layer 4: gate3 fused with (m0*z3+m1*h3)@W4 -> xw4 (overwrites Wt3 — dead) ; z4 = relu(spmm(xw4))
  k_gate4<<<N, 256, 0, stream>>>(h3, z3, Wm3, bm3, W4, xw4);
  k_spmm10<<<ceil_div(N, 256), 256, 0, stream>>>(row_ptr, csr_col, csr_val, xw4, z4, N, 1, 0);
  // final: u gate + fused@W5 -> yb ; out = softmax(spmm(yb))
  k_uy<<<N, 256, 0, stream>>>(z1, z2, z3, z4, zf, Wml, bml, W5, yb);
  k_spmm10<<<ceil_div(N, 256), 256, 0, stream>>>(row_ptr, csr_col, csr_val, yb, out, N, 0, 1);
}